// Round 9
// baseline (254.603 us; speedup 1.0000x reference)
//
#include <hip/hip_runtime.h>

// LJ pair energy -> segment-sum onto first atom of each pair.
// Round-9: XCD-private L2-executed integer atomics.
//
// Established: agent-scope atomics execute at the memory-side coherence point
// (~20.6 G/s, rounds 1-2, per-op 32B write-through). Workgroup-scope global
// atomics omit the device-scope bypass (sc1=0) and execute INSIDE the
// XCD-local L2 (~16 ch/XCD atomic pipes => ~15x higher aggregate rate).
// Safety: copy = PHYSICAL XCD id (s_getreg HW_REG_XCC_ID, 0..7 measured) =>
// each of the 8 integer accumulator copies is only ever RMW'd by waves on its
// own XCD; L2 atomicity covers all CUs of that XCD. Kernel-boundary L2
// writeback publishes the copies to the reduce kernel.
//
// q = round(half_en(d) * 2^15): integer atomics => order-independent =>
// bit-deterministic. |q| <= ~705k; worst-case per-atom sum ~120 pairs *
// 705k ~ 8.5e7 << 2^31 (no overflow).
//
// half_en(d) = 2*((1/d)^12 - (1/d)^6) - e0/2, e0/2 = -2.739720872119788e-3.

#define QSCALE 32768.0f
#define QINV (1.0f / 32768.0f)
#define NXCD 8

static __device__ __forceinline__ float half_en(float d) {
    const float half_e0 = -2.739720872119788e-3f;
    float inv = 1.0f / d;
    float i2 = inv * inv;
    float i6 = i2 * i2 * i2;
    return 2.0f * (i6 * i6 - i6) - half_e0;
}

static __device__ __forceinline__ int quant(float e) {
    int q = __float2int_rn(e * QSCALE);
    return max(-4194304, min(4194303, q));
}

static __device__ __forceinline__ int xcc_id() {
    int x;
    asm volatile("s_getreg_b32 %0, hwreg(HW_REG_XCC_ID)" : "=s"(x));
    return x & (NXCD - 1);
}

static __device__ __forceinline__ void l2_atomic_add(int* p, int v) {
    // Workgroup scope => no device-scope bypass => RMW executes in the
    // XCD-local L2. Non-returning form.
    __hip_atomic_fetch_add(p, v, __ATOMIC_RELAXED, __HIP_MEMORY_SCOPE_WORKGROUP);
}

__global__ __launch_bounds__(256) void lj_atomic_xcd(const float* __restrict__ dist,
                                                     const int* __restrict__ ind2,
                                                     int* __restrict__ ws_int,
                                                     int n_pairs, int natom) {
    int* copy = ws_int + (size_t)xcc_id() * natom;

    const int t = blockIdx.x * blockDim.x + threadIdx.x;
    const int i = t * 4;
    if (i >= n_pairs) return;

    if (i + 4 <= n_pairs) {
        float4 d = *reinterpret_cast<const float4*>(dist + i);
        int4 ia = *reinterpret_cast<const int4*>(ind2 + 2 * i);      // pairs i, i+1
        int4 ib = *reinterpret_cast<const int4*>(ind2 + 2 * i + 4);  // pairs i+2, i+3

        const int q0 = quant(half_en(d.x));
        const int q1 = quant(half_en(d.y));
        const int q2 = quant(half_en(d.z));
        const int q3 = quant(half_en(d.w));

        l2_atomic_add(&copy[ia.x], q0);
        l2_atomic_add(&copy[ia.z], q1);
        l2_atomic_add(&copy[ib.x], q2);
        l2_atomic_add(&copy[ib.z], q3);
    } else {
        for (int p = i; p < n_pairs; ++p)
            l2_atomic_add(&copy[ind2[2 * p]], quant(half_en(dist[p])));
    }
}

__global__ __launch_bounds__(256) void lj_reduce_xcd(const int* __restrict__ ws_int,
                                                     float* __restrict__ out,
                                                     int natom) {
    const int a = blockIdx.x * blockDim.x + threadIdx.x;
    if (a >= natom) return;
    int ssum = 0;
    #pragma unroll
    for (int x = 0; x < NXCD; ++x)
        ssum += ws_int[(size_t)x * natom + a];
    out[a] = (float)ssum * QINV;
}

// Fallback: direct fp device atomics if ws is too small.
__global__ void lj_scatter_direct(const float* __restrict__ dist,
                                  const int* __restrict__ ind2,
                                  float* __restrict__ out,
                                  int n_pairs) {
    int t = blockIdx.x * blockDim.x + threadIdx.x;
    int i = t * 4;
    if (i >= n_pairs) return;
    if (i + 4 <= n_pairs) {
        float4 d = *reinterpret_cast<const float4*>(dist + i);
        int4 ia = *reinterpret_cast<const int4*>(ind2 + 2 * i);
        int4 ib = *reinterpret_cast<const int4*>(ind2 + 2 * i + 4);
        atomicAdd(&out[ia.x], half_en(d.x));
        atomicAdd(&out[ia.z], half_en(d.y));
        atomicAdd(&out[ib.x], half_en(d.z));
        atomicAdd(&out[ib.z], half_en(d.w));
    } else {
        for (int p = i; p < n_pairs; ++p)
            atomicAdd(&out[ind2[2 * p]], half_en(dist[p]));
    }
}

extern "C" void kernel_launch(void* const* d_in, const int* in_sizes, int n_in,
                              void* d_out, int out_size, void* d_ws, size_t ws_size,
                              hipStream_t stream) {
    const float* dist = (const float*)d_in[0];
    // d_in[1] = ind_1: only its shape (natom == out_size) matters.
    const int* ind2 = (const int*)d_in[2];
    float* out = (float*)d_out;

    const int n_pairs = in_sizes[0];
    const int natom = out_size;

    const size_t ws_need = (size_t)NXCD * natom * sizeof(int);

    if (ws_need > ws_size) {
        hipMemsetAsync(d_out, 0, (size_t)out_size * sizeof(float), stream);
        int n_threads = (n_pairs + 3) / 4;
        int grid = (n_threads + 255) / 256;
        lj_scatter_direct<<<grid, 256, 0, stream>>>(dist, ind2, out, n_pairs);
        return;
    }

    int* ws_int = (int*)d_ws;
    hipMemsetAsync(ws_int, 0, ws_need, stream);  // per-call: graph replays

    const int n_threads = (n_pairs + 3) / 4;
    const int grid = (n_threads + 255) / 256;
    lj_atomic_xcd<<<grid, 256, 0, stream>>>(dist, ind2, ws_int, n_pairs, natom);

    const int rgrid = (natom + 255) / 256;
    lj_reduce_xcd<<<rgrid, 256, 0, stream>>>(ws_int, out, natom);
}

// Round 10
// 55.721 us; speedup vs baseline: 4.5692x; 4.5692x over previous
//
#include <hip/hip_runtime.h>

// LJ pair energy -> segment-sum onto first atom of each pair, no fp atomics.
// Round-10: bucket-major global regions via per-block cursor reservation.
//   K1 lj_bin (512 thr, CHUNK=8192): q = round(half_en(d)*2^15), bucket =
//      atom>>9 (512 atoms/bucket, nb=196). LDS rank (atomicAdd cnt[b]) ->
//      shfl scan -> offs; ONE device atomicAdd per (block,bucket) reserves
//      space in region(b, s=c%8) (153K total cursor atomics, overlapped);
//      records (q<<9|local) sorted in LDS then streamed out so each ~42-rec
//      run is contiguous at region(b,s)+base+runidx (coalesced bursts).
//   K2 lj_red (196 blocks x 1024 thr): per bucket, stream the 8 contiguous
//      regions (no offset table, no dependent loads; wave w -> slice w&7),
//      LDS int acc[512], write final floats directly. No partials, no K3.
// Int accumulation commutes => cursor-order nondeterminism still yields a
// bit-deterministic result across graph replays.
//
// half_en(d) = 2*((1/d)^12 - (1/d)^6) - e0/2, e0/2 = -2.739720872119788e-3.
// |half_en| <= ~23.3 for d >= 0.8 -> |q| <= ~764k < 2^22 (23-bit field).

#define CHUNK 8192
#define T1 512
#define ABITS 9
#define APB 512              // atoms per bucket
#define QSCALE 32768.0f      // 2^15
#define QINV (1.0f / 32768.0f)
#define NS 8                 // slices == XCD count (locality heuristic only)
#define CAP 16384            // records per (bucket,slice) region (4x expected)
#define T2 1024

static __device__ __forceinline__ float half_en(float d) {
    const float half_e0 = -2.739720872119788e-3f;
    float inv = 1.0f / d;
    float i2 = inv * inv;
    float i6 = i2 * i2 * i2;
    return 2.0f * (i6 * i6 - i6) - half_e0;
}

static __device__ __forceinline__ int quant(float e) {
    int q = __float2int_rn(e * QSCALE);
    return max(-4194304, min(4194303, q));  // 23-bit signed
}

__global__ __launch_bounds__(T1) void lj_bin(const float* __restrict__ dist,
                                             const int* __restrict__ ind2,
                                             unsigned* __restrict__ grec,
                                             unsigned* __restrict__ cursor,
                                             int n_pairs, int nb) {
    __shared__ unsigned cnt[256];
    __shared__ unsigned offs[256];
    __shared__ unsigned wsum[4];
    __shared__ unsigned gbase[256];
    __shared__ unsigned recs[CHUNK];
    __shared__ unsigned char bposs[CHUNK];

    const int t = threadIdx.x;
    const int c = blockIdx.x;
    const int base = c * CHUNK;
    const int s = c & (NS - 1);

    if (t < 256) cnt[t] = 0;
    __syncthreads();

    unsigned rec[16];
    unsigned br[16];  // (bucket<<16) | rank ; 0xFFFFFFFF = invalid

    #pragma unroll
    for (int g = 0; g < 4; ++g) {
        const int p0 = base + g * (T1 * 4) + t * 4;
        float dd[4] = {0.f, 0.f, 0.f, 0.f};
        int ii[4] = {0, 0, 0, 0};
        if (p0 + 4 <= n_pairs) {
            float4 d = *reinterpret_cast<const float4*>(dist + p0);
            int4 ia = *reinterpret_cast<const int4*>(ind2 + 2 * p0);
            int4 ib = *reinterpret_cast<const int4*>(ind2 + 2 * p0 + 4);
            dd[0] = d.x; dd[1] = d.y; dd[2] = d.z; dd[3] = d.w;
            ii[0] = ia.x; ii[1] = ia.z; ii[2] = ib.x; ii[3] = ib.z;
        } else {
            #pragma unroll
            for (int k = 0; k < 4; ++k)
                if (p0 + k < n_pairs) { dd[k] = dist[p0 + k]; ii[k] = ind2[2 * (p0 + k)]; }
        }
        #pragma unroll
        for (int k = 0; k < 4; ++k) {
            const int j = g * 4 + k;
            if (p0 + k < n_pairs) {
                const int id = ii[k];
                const int b = id >> ABITS;
                const int q = quant(half_en(dd[k]));
                rec[j] = (((unsigned)q) << ABITS) | (unsigned)(id & (APB - 1));
                const unsigned rank = atomicAdd(&cnt[b], 1u);  // rank within bucket
                br[j] = ((unsigned)b << 16) | rank;            // rank < 8192 fits
            } else {
                br[j] = 0xFFFFFFFFu;
                rec[j] = 0;
            }
        }
    }
    __syncthreads();

    // Exclusive scan of cnt[0..255]: per-wave shfl scan + wave-total fixup.
    {
        const unsigned v = (t < 256) ? cnt[t] : 0u;
        unsigned inc = v;
        #pragma unroll
        for (int d = 1; d < 64; d <<= 1) {
            const unsigned x = __shfl_up(inc, d, 64);
            if ((t & 63) >= d) inc += x;
        }
        if (t < 256 && (t & 63) == 63) wsum[t >> 6] = inc;
        __syncthreads();
        if (t < 256) {
            unsigned add = 0;
            #pragma unroll
            for (int j = 0; j < 4; ++j)
                if (j < (t >> 6)) add += wsum[j];
            offs[t] = add + inc - v;  // exclusive
        }
    }
    __syncthreads();

    // Reserve space in global bucket-major regions (one atomic per bucket).
    if (t < nb) {
        const unsigned n = cnt[t];
        gbase[t] = n ? atomicAdd(&cursor[(unsigned)t * NS + s], n) : 0u;
    }

    // Sort records into LDS by bucket (rank trick); remember bucket per slot.
    #pragma unroll
    for (int j = 0; j < 16; ++j) {
        if (br[j] != 0xFFFFFFFFu) {
            const unsigned b = br[j] >> 16;
            const unsigned pos = offs[b] + (br[j] & 0xFFFFu);
            recs[pos] = rec[j];
            bposs[pos] = (unsigned char)b;
        }
    }
    __syncthreads();

    // Stream out: consecutive i -> consecutive addresses within each run.
    const int nv = min(CHUNK, n_pairs - base);
    for (int i = t; i < nv; i += T1) {
        const unsigned b = bposs[i];
        const unsigned ridx = gbase[b] + (unsigned)i - offs[b];
        if (ridx < CAP)  // safety clamp; never hit for this input (4x headroom)
            grec[((size_t)b * NS + s) * CAP + ridx] = recs[i];
    }
}

__global__ __launch_bounds__(T2) void lj_red(const unsigned* __restrict__ grec,
                                             const unsigned* __restrict__ cursor,
                                             float* __restrict__ out,
                                             int natom, int nb) {
    __shared__ int acc[APB];
    const int t = threadIdx.x;
    const int b = blockIdx.x;

    if (t < APB) acc[t] = 0;
    __syncthreads();

    // wave w (0..15) -> slice s = w&7, half = w>>3; stream contiguous region.
    const int w = t >> 6;
    const int s = w & (NS - 1);
    const int half = w >> 3;
    const int lane = t & 63;

    unsigned n = cursor[(unsigned)b * NS + s];
    if (n > CAP) n = CAP;
    const unsigned* rg = grec + ((size_t)b * NS + s) * CAP;
    for (unsigned i = (unsigned)(half * 64 + lane); i < n; i += 128) {
        const unsigned r = rg[i];
        atomicAdd(&acc[r & (APB - 1)], ((int)r) >> ABITS);
    }
    __syncthreads();

    if (t < APB) {
        const int a = b * APB + t;
        if (a < natom) out[a] = (float)acc[t] * QINV;
    }
}

// Fallback: direct fp device atomics if ws too small / shape unexpected.
__global__ void lj_scatter_direct(const float* __restrict__ dist,
                                  const int* __restrict__ ind2,
                                  float* __restrict__ out,
                                  int n_pairs) {
    int t = blockIdx.x * blockDim.x + threadIdx.x;
    int i = t * 4;
    if (i >= n_pairs) return;
    if (i + 4 <= n_pairs) {
        float4 d = *reinterpret_cast<const float4*>(dist + i);
        int4 ia = *reinterpret_cast<const int4*>(ind2 + 2 * i);
        int4 ib = *reinterpret_cast<const int4*>(ind2 + 2 * i + 4);
        atomicAdd(&out[ia.x], half_en(d.x));
        atomicAdd(&out[ia.z], half_en(d.y));
        atomicAdd(&out[ib.x], half_en(d.z));
        atomicAdd(&out[ib.z], half_en(d.w));
    } else {
        for (int p = i; p < n_pairs; ++p)
            atomicAdd(&out[ind2[2 * p]], half_en(dist[p]));
    }
}

extern "C" void kernel_launch(void* const* d_in, const int* in_sizes, int n_in,
                              void* d_out, int out_size, void* d_ws, size_t ws_size,
                              hipStream_t stream) {
    const float* dist = (const float*)d_in[0];
    // d_in[1] = ind_1: only its shape (natom == out_size) matters.
    const int* ind2 = (const int*)d_in[2];
    float* out = (float*)d_out;

    const int n_pairs = in_sizes[0];
    const int natom = out_size;

    const int nchunk = (n_pairs + CHUNK - 1) / CHUNK;
    const int nb = (natom + APB - 1) / APB;

    const size_t rec_bytes = (size_t)nb * NS * CAP * sizeof(unsigned);
    const size_t cur_bytes = (size_t)nb * NS * sizeof(unsigned);
    const size_t need = rec_bytes + cur_bytes;

    if (nb > 256 || need > ws_size) {
        hipMemsetAsync(d_out, 0, (size_t)out_size * sizeof(float), stream);
        int n_threads = (n_pairs + 3) / 4;
        int grid = (n_threads + 255) / 256;
        lj_scatter_direct<<<grid, 256, 0, stream>>>(dist, ind2, out, n_pairs);
        return;
    }

    unsigned* grec = (unsigned*)d_ws;
    unsigned* cursor = (unsigned*)((char*)d_ws + rec_bytes);

    hipMemsetAsync(cursor, 0, cur_bytes, stream);  // per-call: graph replays
    lj_bin<<<nchunk, T1, 0, stream>>>(dist, ind2, grec, cursor, n_pairs, nb);
    lj_red<<<nb, T2, 0, stream>>>(grec, cursor, out, natom, nb);
}

// Round 11
// 41.057 us; speedup vs baseline: 6.2012x; 1.3572x over previous
//
#include <hip/hip_runtime.h>

// LJ pair energy -> segment-sum onto first atom of each pair, no fp atomics.
// Round-11: r7 pipeline + split LDS counters in K1 (halve rank-atomic
// serialization). Established facts driving this design:
//   * Any global RMW (any scope, any spread) ~20-26 G ops/s wall (r1/r2/r9).
//   * LDS-sort + coalesced copy-out beats direct scattered stores (r8/r10).
//   * XCD-striped record round-trip is worth ~3 us (r7).
//   K1 lj_bin (512 thr, CHUNK=8192): q = round(half_en(d)*2^15) (23b clamp),
//      bucket = atom>>9 (512 atoms/bucket, nb=196). rank = LDS atomicAdd on
//      the HALF-BLOCK's private counter bank (cntA: threads 0-255, cntB:
//      256-511); shfl scan over cntA+cntB -> offs; records (q<<9|local)
//      grouped in LDS at offs[b] + (half?cntA[b]:0) + rank; uint4 coalesced
//      region write; offset row transposed goffs[(b*NS+s)*P + c/NS], s=c%NS.
//   K2 lj_bucket_reduce (grid vb = b*NS+s): slice s owns chunks c≡s (mod NS)
//      -> same-XCD L2 record reads. Preload lo/hi rows; 2x32 lane-split run
//      gather; LDS int acc[512]; write int partial[s].
//   K3 lj_final: out[a] = (sum_{s<8} partial[s][a]) * 2^-15.
// Integer accumulation => bit-deterministic output across graph replays.
//
// half_en(d) = 2*((1/d)^12 - (1/d)^6) - e0/2, e0/2 = -2.739720872119788e-3.
// |half_en| <= ~23.3 for d >= 0.8 -> |q| <= ~764k < 2^22 (23-bit field).

#define CHUNK 8192
#define T1 512
#define ABITS 9
#define APB 512             // atoms per bucket
#define QSCALE 32768.0f     // 2^15
#define QINV (1.0f / 32768.0f)
#define NS 8                // slices == XCD count
#define MAXCPS 160          // max chunks per slice (P)
#define T2 256

static __device__ __forceinline__ float half_en(float d) {
    const float half_e0 = -2.739720872119788e-3f;
    float inv = 1.0f / d;
    float i2 = inv * inv;
    float i6 = i2 * i2 * i2;
    return 2.0f * (i6 * i6 - i6) - half_e0;
}

static __device__ __forceinline__ int quant(float e) {
    int q = __float2int_rn(e * QSCALE);
    return max(-4194304, min(4194303, q));  // 23-bit signed
}

__global__ __launch_bounds__(T1) void lj_bin(const float* __restrict__ dist,
                                             const int* __restrict__ ind2,
                                             unsigned* __restrict__ grec,
                                             unsigned* __restrict__ goffs,
                                             int n_pairs, int nchunk, int nb, int P) {
    __shared__ unsigned cntA[256];
    __shared__ unsigned cntB[256];
    __shared__ unsigned offs[256];
    __shared__ unsigned wsum[4];
    __shared__ unsigned recs[CHUNK];

    const int t = threadIdx.x;
    const int c = blockIdx.x;
    const int base = c * CHUNK;
    const int half = t >> 8;               // 0: threads 0-255, 1: 256-511

    if (t < 256) { cntA[t] = 0; } else { cntB[t - 256] = 0; }
    __syncthreads();

    unsigned* mycnt = half ? cntB : cntA;

    unsigned rec[16];
    unsigned br[16];  // (bucket<<16) | (half<<15) | rank ; 0xFFFFFFFF = invalid

    #pragma unroll
    for (int g = 0; g < 4; ++g) {
        const int p0 = base + g * (T1 * 4) + t * 4;
        float dd[4] = {0.f, 0.f, 0.f, 0.f};
        int ii[4] = {0, 0, 0, 0};
        if (p0 + 4 <= n_pairs) {
            float4 d = *reinterpret_cast<const float4*>(dist + p0);
            int4 ia = *reinterpret_cast<const int4*>(ind2 + 2 * p0);
            int4 ib = *reinterpret_cast<const int4*>(ind2 + 2 * p0 + 4);
            dd[0] = d.x; dd[1] = d.y; dd[2] = d.z; dd[3] = d.w;
            ii[0] = ia.x; ii[1] = ia.z; ii[2] = ib.x; ii[3] = ib.z;
        } else {
            #pragma unroll
            for (int k = 0; k < 4; ++k)
                if (p0 + k < n_pairs) { dd[k] = dist[p0 + k]; ii[k] = ind2[2 * (p0 + k)]; }
        }
        #pragma unroll
        for (int k = 0; k < 4; ++k) {
            const int j = g * 4 + k;
            if (p0 + k < n_pairs) {
                const int id = ii[k];
                const int b = id >> ABITS;
                const int q = quant(half_en(dd[k]));
                rec[j] = (((unsigned)q) << ABITS) | (unsigned)(id & (APB - 1));
                const unsigned rank = atomicAdd(&mycnt[b], 1u);  // rank in half
                br[j] = ((unsigned)b << 16) | ((unsigned)half << 15) | rank;
            } else {
                br[j] = 0xFFFFFFFFu;  // bucket field 0xFFFF > nb -> invalid
                rec[j] = 0;
            }
        }
    }
    __syncthreads();

    // Exclusive scan of (cntA+cntB)[0..255]: per-wave shfl + wave-total fixup.
    {
        const unsigned v = (t < 256) ? (cntA[t] + cntB[t]) : 0u;
        unsigned inc = v;
        #pragma unroll
        for (int d = 1; d < 64; d <<= 1) {
            const unsigned x = __shfl_up(inc, d, 64);
            if ((t & 63) >= d) inc += x;
        }
        if (t < 256 && (t & 63) == 63) wsum[t >> 6] = inc;
        __syncthreads();
        if (t < 256) {
            unsigned add = 0;
            #pragma unroll
            for (int j = 0; j < 4; ++j)
                if (j < (t >> 6)) add += wsum[j];
            offs[t] = add + inc - v;  // exclusive over bucket totals
        }
    }
    __syncthreads();

    // Place records grouped by bucket: [half0's recs | half1's recs] per bucket.
    #pragma unroll
    for (int j = 0; j < 16; ++j) {
        const unsigned bj = br[j] >> 16;
        if (bj < 256u) {
            const unsigned h = (br[j] >> 15) & 1u;
            const unsigned rank = br[j] & 0x7FFFu;
            const unsigned pos = offs[bj] + (h ? cntA[bj] : 0u) + rank;
            recs[pos] = rec[j];
        }
    }
    __syncthreads();

    const int nv = min(CHUNK, n_pairs - base);
    for (int i4 = t * 4; i4 + 4 <= nv; i4 += T1 * 4) {
        uint4 v = *reinterpret_cast<const uint4*>(&recs[i4]);
        *reinterpret_cast<uint4*>(&grec[(size_t)base + i4]) = v;
    }
    for (int i = (nv & ~3) + t; i < nv; i += T1)
        grec[(size_t)base + i] = recs[i];
    // Transposed offset row: (bucket t, slice s=c%NS), column cc=c/NS.
    // Row nb is the end sentinel (offs[nb] = chunk's valid count).
    if (t <= nb)
        goffs[((size_t)t * NS + (c & (NS - 1))) * P + (c >> 3)] = offs[t];
}

__global__ __launch_bounds__(T2) void lj_bucket_reduce(const unsigned* __restrict__ grec,
                                                       const unsigned* __restrict__ goffs,
                                                       int* __restrict__ partial,
                                                       int nchunk, int nb, int natom_pad,
                                                       int P) {
    __shared__ int acc[APB];
    __shared__ unsigned lo[MAXCPS];
    __shared__ unsigned hi[MAXCPS];

    const int t = threadIdx.x;
    const int vb = blockIdx.x;
    const int s = vb & (NS - 1);   // slice -> same XCD as its chunks (heuristic)
    const int b = vb >> 3;         // NS == 8

    #pragma unroll
    for (int k = 0; k < APB / T2; ++k) acc[t + k * T2] = 0;

    // Slice s owns chunks c = s + NS*cc, cc in [0, cn).
    const int cn = (nchunk - s + NS - 1) >> 3;
    if (cn > 0) {
        const unsigned* r0 = goffs + ((size_t)b * NS + s) * P;
        const unsigned* r1 = goffs + ((size_t)(b + 1) * NS + s) * P;
        for (int i = t; i < cn; i += T2) { lo[i] = r0[i]; hi[i] = r1[i]; }
    }
    __syncthreads();

    if (cn > 0) {
        // Each wave handles TWO runs at once (lanes 0-31 / 32-63).
        const int wv = t >> 6;
        const int half = (t >> 5) & 1;
        const int sub = t & 31;
        for (int cc = wv * 2; cc < cn; cc += (T2 / 64) * 2) {
            const int myrun = cc + half;
            if (myrun < cn) {
                const unsigned o0 = lo[myrun];
                const unsigned o1 = hi[myrun];
                const size_t rb = (size_t)(s + myrun * NS) * CHUNK;
                for (unsigned i = o0 + sub; i < o1; i += 32) {
                    const unsigned r = grec[rb + i];
                    atomicAdd(&acc[r & (APB - 1)], ((int)r) >> ABITS);
                }
            }
        }
    }
    __syncthreads();

    int* dst = partial + (size_t)s * natom_pad + (size_t)b * APB;
    #pragma unroll
    for (int k = 0; k < APB / T2; ++k) dst[t + k * T2] = acc[t + k * T2];
}

__global__ void lj_final(const int* __restrict__ partial, float* __restrict__ out,
                         int natom, int natom_pad) {
    const int a = blockIdx.x * blockDim.x + threadIdx.x;
    if (a >= natom) return;
    int ssum = 0;
    #pragma unroll
    for (int s = 0; s < NS; ++s)
        ssum += partial[(size_t)s * natom_pad + a];
    out[a] = (float)ssum * QINV;
}

// Fallback: direct fp device atomics if ws too small / shape unexpected.
__global__ void lj_scatter_direct(const float* __restrict__ dist,
                                  const int* __restrict__ ind2,
                                  float* __restrict__ out,
                                  int n_pairs) {
    int t = blockIdx.x * blockDim.x + threadIdx.x;
    int i = t * 4;
    if (i >= n_pairs) return;
    if (i + 4 <= n_pairs) {
        float4 d = *reinterpret_cast<const float4*>(dist + i);
        int4 ia = *reinterpret_cast<const int4*>(ind2 + 2 * i);
        int4 ib = *reinterpret_cast<const int4*>(ind2 + 2 * i + 4);
        atomicAdd(&out[ia.x], half_en(d.x));
        atomicAdd(&out[ia.z], half_en(d.y));
        atomicAdd(&out[ib.x], half_en(d.z));
        atomicAdd(&out[ib.z], half_en(d.w));
    } else {
        for (int p = i; p < n_pairs; ++p)
            atomicAdd(&out[ind2[2 * p]], half_en(dist[p]));
    }
}

extern "C" void kernel_launch(void* const* d_in, const int* in_sizes, int n_in,
                              void* d_out, int out_size, void* d_ws, size_t ws_size,
                              hipStream_t stream) {
    const float* dist = (const float*)d_in[0];
    // d_in[1] = ind_1: only its shape (natom == out_size) matters.
    const int* ind2 = (const int*)d_in[2];
    float* out = (float*)d_out;

    const int n_pairs = in_sizes[0];
    const int natom = out_size;

    const int nchunk = (n_pairs + CHUNK - 1) / CHUNK;
    const int nb = (natom + APB - 1) / APB;
    const int natom_pad = nb * APB;
    const int P = (nchunk + NS - 1) / NS;   // max chunks per slice

    const size_t rec_bytes = (size_t)nchunk * CHUNK * sizeof(unsigned);
    const size_t offs_bytes = (size_t)(nb + 1) * NS * P * sizeof(unsigned);
    const size_t part_bytes = (size_t)NS * natom_pad * sizeof(int);
    const size_t need = rec_bytes + offs_bytes + part_bytes;

    if (nb + 1 > 256 || P > MAXCPS || need > ws_size) {
        hipMemsetAsync(d_out, 0, (size_t)out_size * sizeof(float), stream);
        int n_threads = (n_pairs + 3) / 4;
        int grid = (n_threads + 255) / 256;
        lj_scatter_direct<<<grid, 256, 0, stream>>>(dist, ind2, out, n_pairs);
        return;
    }

    unsigned* grec = (unsigned*)d_ws;
    unsigned* goffs = (unsigned*)((char*)d_ws + rec_bytes);
    int* partial = (int*)((char*)d_ws + rec_bytes + offs_bytes);

    lj_bin<<<nchunk, T1, 0, stream>>>(dist, ind2, grec, goffs, n_pairs, nchunk, nb, P);
    lj_bucket_reduce<<<NS * nb, T2, 0, stream>>>(grec, goffs, partial,
                                                 nchunk, nb, natom_pad, P);
    int fgrid = (natom + 255) / 256;
    lj_final<<<fgrid, 256, 0, stream>>>(partial, out, natom, natom_pad);
}

// Round 12
// 40.270 us; speedup vs baseline: 6.3224x; 1.0195x over previous
//
#include <hip/hip_runtime.h>

// LJ pair energy -> segment-sum onto first atom of each pair, no fp atomics.
// FINAL (= round-7 best, 40.3 us): counting-sort pipeline + XCD-local record
// striping. Session-established facts this design rests on:
//   * Any global RMW (fp or int, agent or workgroup scope, padded or not)
//     executes at the memory-side point: ~20-26 G ops/s, 32 B/op write-through
//     (r1/r2/r9). 6.4M pairs => >=250 us for ANY atomic formulation.
//   * LDS-sort + coalesced copy-out beats direct scattered global stores
//     (r8/r10); K1's cost is NOT LDS-atomic rank contention (r11 A/B null).
//   * Device-scope fences per-block are us-class poison (r8).
//   * XCD-striping the record round-trip (slice s owns chunks c%8==s,
//     reducer vb%8=s lands on the same XCD via round-robin dispatch) = +3 us.
//   K1 lj_bin (512 thr, CHUNK=8192): q = round(half_en(d)*2^15) (23b clamp),
//      bucket = atom>>9 (512 atoms/bucket, nb=196). rank = LDS atomicAdd;
//      shfl scan -> offs; records (q<<9|local) grouped in LDS; uint4 coalesced
//      region write; offset row transposed goffs[(b*NS+s)*P + c/NS], s=c%NS.
//   K2 lj_bucket_reduce (grid vb = b*NS+s): preload lo/hi offset rows to LDS;
//      2x32 lane-split run gather; LDS int acc[512]; write int partial[s].
//   K3 lj_final: out[a] = (sum_{s<8} partial[s][a]) * 2^-15.
// Integer accumulation => bit-deterministic output across graph replays.
//
// half_en(d) = 2*((1/d)^12 - (1/d)^6) - e0/2, e0/2 = -2.739720872119788e-3.
// |half_en| <= ~23.3 for d >= 0.8 -> |q| <= ~764k < 2^22 (23-bit field).

#define CHUNK 8192
#define T1 512
#define ABITS 9
#define APB 512             // atoms per bucket
#define QSCALE 32768.0f     // 2^15
#define QINV (1.0f / 32768.0f)
#define NS 8                // slices == XCD count
#define MAXCPS 160          // max chunks per slice (P)
#define T2 256

static __device__ __forceinline__ float half_en(float d) {
    const float half_e0 = -2.739720872119788e-3f;
    float inv = 1.0f / d;
    float i2 = inv * inv;
    float i6 = i2 * i2 * i2;
    return 2.0f * (i6 * i6 - i6) - half_e0;
}

static __device__ __forceinline__ int quant(float e) {
    int q = __float2int_rn(e * QSCALE);
    return max(-4194304, min(4194303, q));  // 23-bit signed
}

__global__ __launch_bounds__(T1) void lj_bin(const float* __restrict__ dist,
                                             const int* __restrict__ ind2,
                                             unsigned* __restrict__ grec,
                                             unsigned* __restrict__ goffs,
                                             int n_pairs, int nchunk, int nb, int P) {
    __shared__ unsigned cnt[256];
    __shared__ unsigned offs[256];
    __shared__ unsigned wsum[8];
    __shared__ unsigned recs[CHUNK];

    const int t = threadIdx.x;
    const int c = blockIdx.x;
    const int base = c * CHUNK;

    if (t < 256) cnt[t] = 0;
    __syncthreads();

    unsigned rec[16];
    unsigned br[16];  // (bucket<<16) | rank ; 0xFFFFFFFF = invalid

    #pragma unroll
    for (int g = 0; g < 4; ++g) {
        const int p0 = base + g * (T1 * 4) + t * 4;
        float dd[4] = {0.f, 0.f, 0.f, 0.f};
        int ii[4] = {0, 0, 0, 0};
        if (p0 + 4 <= n_pairs) {
            float4 d = *reinterpret_cast<const float4*>(dist + p0);
            int4 ia = *reinterpret_cast<const int4*>(ind2 + 2 * p0);
            int4 ib = *reinterpret_cast<const int4*>(ind2 + 2 * p0 + 4);
            dd[0] = d.x; dd[1] = d.y; dd[2] = d.z; dd[3] = d.w;
            ii[0] = ia.x; ii[1] = ia.z; ii[2] = ib.x; ii[3] = ib.z;
        } else {
            #pragma unroll
            for (int k = 0; k < 4; ++k)
                if (p0 + k < n_pairs) { dd[k] = dist[p0 + k]; ii[k] = ind2[2 * (p0 + k)]; }
        }
        #pragma unroll
        for (int k = 0; k < 4; ++k) {
            const int j = g * 4 + k;
            if (p0 + k < n_pairs) {
                const int id = ii[k];
                const int b = id >> ABITS;
                const int q = quant(half_en(dd[k]));
                rec[j] = (((unsigned)q) << ABITS) | (unsigned)(id & (APB - 1));
                const unsigned rank = atomicAdd(&cnt[b], 1u);  // rank within bucket
                br[j] = ((unsigned)b << 16) | rank;            // rank < 8192 fits
            } else {
                br[j] = 0xFFFFFFFFu;
                rec[j] = 0;
            }
        }
    }
    __syncthreads();

    // Exclusive scan of cnt[0..255]: per-wave shfl scan + wave-total fixup.
    {
        const unsigned v = (t < 256) ? cnt[t] : 0u;
        unsigned inc = v;
        #pragma unroll
        for (int d = 1; d < 64; d <<= 1) {
            const unsigned x = __shfl_up(inc, d, 64);
            if ((t & 63) >= d) inc += x;
        }
        if (t < 256 && (t & 63) == 63) wsum[t >> 6] = inc;
        __syncthreads();
        if (t < 256) {
            unsigned add = 0;
            #pragma unroll
            for (int j = 0; j < 4; ++j)
                if (j < (t >> 6)) add += wsum[j];
            offs[t] = add + inc - v;  // exclusive
        }
    }
    __syncthreads();

    // Place records grouped by bucket (rank trick, single atomic round).
    #pragma unroll
    for (int j = 0; j < 16; ++j) {
        if (br[j] != 0xFFFFFFFFu) {
            const unsigned pos = offs[br[j] >> 16] + (br[j] & 0xFFFFu);
            recs[pos] = rec[j];
        }
    }
    __syncthreads();

    const int nv = min(CHUNK, n_pairs - base);
    for (int i4 = t * 4; i4 + 4 <= nv; i4 += T1 * 4) {
        uint4 v = *reinterpret_cast<const uint4*>(&recs[i4]);
        *reinterpret_cast<uint4*>(&grec[(size_t)base + i4]) = v;
    }
    for (int i = (nv & ~3) + t; i < nv; i += T1)
        grec[(size_t)base + i] = recs[i];
    // Transposed offset write: row (bucket t, slice s=c%NS), column cc=c/NS.
    // Row nb is the end sentinel (offs[nb] = nv since cnt[b>=nb]=0).
    if (t <= nb)
        goffs[((size_t)t * NS + (c & (NS - 1))) * P + (c >> 3)] = offs[t];
}

__global__ __launch_bounds__(T2) void lj_bucket_reduce(const unsigned* __restrict__ grec,
                                                       const unsigned* __restrict__ goffs,
                                                       int* __restrict__ partial,
                                                       int nchunk, int nb, int natom_pad,
                                                       int P) {
    __shared__ int acc[APB];
    __shared__ unsigned lo[MAXCPS];
    __shared__ unsigned hi[MAXCPS];

    const int t = threadIdx.x;
    const int vb = blockIdx.x;
    const int s = vb & (NS - 1);   // slice -> same XCD as its chunks (heuristic)
    const int b = vb >> 3;         // NS == 8

    #pragma unroll
    for (int k = 0; k < APB / T2; ++k) acc[t + k * T2] = 0;

    // Slice s owns chunks c = s + NS*cc, cc in [0, cn).
    const int cn = (nchunk - s + NS - 1) >> 3;
    if (cn > 0) {
        const unsigned* r0 = goffs + ((size_t)b * NS + s) * P;
        const unsigned* r1 = goffs + ((size_t)(b + 1) * NS + s) * P;
        for (int i = t; i < cn; i += T2) { lo[i] = r0[i]; hi[i] = r1[i]; }
    }
    __syncthreads();

    if (cn > 0) {
        // Each wave handles TWO runs at once (lanes 0-31 / 32-63).
        const int wv = t >> 6;
        const int half = (t >> 5) & 1;
        const int sub = t & 31;
        for (int cc = wv * 2; cc < cn; cc += (T2 / 64) * 2) {
            const int myrun = cc + half;
            if (myrun < cn) {
                const unsigned o0 = lo[myrun];
                const unsigned o1 = hi[myrun];
                const size_t rb = (size_t)(s + myrun * NS) * CHUNK;
                for (unsigned i = o0 + sub; i < o1; i += 32) {
                    const unsigned r = grec[rb + i];
                    atomicAdd(&acc[r & (APB - 1)], ((int)r) >> ABITS);
                }
            }
        }
    }
    __syncthreads();

    int* dst = partial + (size_t)s * natom_pad + (size_t)b * APB;
    #pragma unroll
    for (int k = 0; k < APB / T2; ++k) dst[t + k * T2] = acc[t + k * T2];
}

__global__ void lj_final(const int* __restrict__ partial, float* __restrict__ out,
                         int natom, int natom_pad) {
    const int a = blockIdx.x * blockDim.x + threadIdx.x;
    if (a >= natom) return;
    int ssum = 0;
    #pragma unroll
    for (int s = 0; s < NS; ++s)
        ssum += partial[(size_t)s * natom_pad + a];
    out[a] = (float)ssum * QINV;
}

// Fallback: direct fp device atomics if ws too small / shape unexpected.
__global__ void lj_scatter_direct(const float* __restrict__ dist,
                                  const int* __restrict__ ind2,
                                  float* __restrict__ out,
                                  int n_pairs) {
    int t = blockIdx.x * blockDim.x + threadIdx.x;
    int i = t * 4;
    if (i >= n_pairs) return;
    if (i + 4 <= n_pairs) {
        float4 d = *reinterpret_cast<const float4*>(dist + i);
        int4 ia = *reinterpret_cast<const int4*>(ind2 + 2 * i);
        int4 ib = *reinterpret_cast<const int4*>(ind2 + 2 * i + 4);
        atomicAdd(&out[ia.x], half_en(d.x));
        atomicAdd(&out[ia.z], half_en(d.y));
        atomicAdd(&out[ib.x], half_en(d.z));
        atomicAdd(&out[ib.z], half_en(d.w));
    } else {
        for (int p = i; p < n_pairs; ++p)
            atomicAdd(&out[ind2[2 * p]], half_en(dist[p]));
    }
}

extern "C" void kernel_launch(void* const* d_in, const int* in_sizes, int n_in,
                              void* d_out, int out_size, void* d_ws, size_t ws_size,
                              hipStream_t stream) {
    const float* dist = (const float*)d_in[0];
    // d_in[1] = ind_1: only its shape (natom == out_size) matters.
    const int* ind2 = (const int*)d_in[2];
    float* out = (float*)d_out;

    const int n_pairs = in_sizes[0];
    const int natom = out_size;

    const int nchunk = (n_pairs + CHUNK - 1) / CHUNK;
    const int nb = (natom + APB - 1) / APB;
    const int natom_pad = nb * APB;
    const int P = (nchunk + NS - 1) / NS;   // max chunks per slice

    const size_t rec_bytes = (size_t)nchunk * CHUNK * sizeof(unsigned);
    const size_t offs_bytes = (size_t)(nb + 1) * NS * P * sizeof(unsigned);
    const size_t part_bytes = (size_t)NS * natom_pad * sizeof(int);
    const size_t need = rec_bytes + offs_bytes + part_bytes;

    if (nb + 1 > 256 || P > MAXCPS || need > ws_size) {
        hipMemsetAsync(d_out, 0, (size_t)out_size * sizeof(float), stream);
        int n_threads = (n_pairs + 3) / 4;
        int grid = (n_threads + 255) / 256;
        lj_scatter_direct<<<grid, 256, 0, stream>>>(dist, ind2, out, n_pairs);
        return;
    }

    unsigned* grec = (unsigned*)d_ws;
    unsigned* goffs = (unsigned*)((char*)d_ws + rec_bytes);
    int* partial = (int*)((char*)d_ws + rec_bytes + offs_bytes);

    lj_bin<<<nchunk, T1, 0, stream>>>(dist, ind2, grec, goffs, n_pairs, nchunk, nb, P);
    lj_bucket_reduce<<<NS * nb, T2, 0, stream>>>(grec, goffs, partial,
                                                 nchunk, nb, natom_pad, P);
    int fgrid = (natom + 255) / 256;
    lj_final<<<fgrid, 256, 0, stream>>>(partial, out, natom, natom_pad);
}